// Round 11
// baseline (101.506 us; speedup 1.0000x reference)
//
#include <hip/hip_runtime.h>
#include <math.h>

#define BATCH 4
#define SEQ   1024
#define DIN   512
#define DKQ   512
#define DV    64
#define NH    64

typedef __attribute__((ext_vector_type(8))) short short8v;   // 8 bf16 = 4 VGPRs
typedef __attribute__((ext_vector_type(4))) float float4v;
typedef __attribute__((ext_vector_type(4))) unsigned int uint4v;

__device__ __forceinline__ void split_bf16(float f, unsigned short& hi, unsigned short& lo) {
    unsigned int u = __float_as_uint(f);
    hi = (unsigned short)(u >> 16);
    float l = f - __uint_as_float(u & 0xFFFF0000u);
    lo = (unsigned short)(__float_as_uint(l) >> 16);
}
__device__ __forceinline__ unsigned short f32_to_bf16_rne(float f) {
    unsigned int u = __float_as_uint(f);
    u += 0x7FFFu + ((u >> 16) & 1u);
    return (unsigned short)(u >> 16);
}
__device__ __forceinline__ float bf16_bits_to_f32(unsigned short s) {
    return __uint_as_float((unsigned int)s << 16);
}

// async global -> LDS, 16B per lane; LDS dest = wave-uniform base + lane*16
__device__ __forceinline__ void gll16(const unsigned short* g, unsigned short* l) {
    __builtin_amdgcn_global_load_lds(
        (const __attribute__((address_space(1))) unsigned int*)(g),
        (__attribute__((address_space(3))) unsigned int*)(l),
        16, 0, 0);
}

// ---------------------------------------------------------------------------
// prepack: z=0..2 -> W transpose+split planes; z=3 -> x split planes + obuf.
// grid (16,16,4), block (32,8).  (unchanged)
// ---------------------------------------------------------------------------
__global__ __launch_bounds__(256)
void prepack(const float* __restrict__ x,
             const float* __restrict__ Wq, const float* __restrict__ Wk,
             const float* __restrict__ Wv,
             unsigned short* __restrict__ WhiQ, unsigned short* __restrict__ WloQ,
             unsigned short* __restrict__ WhiK, unsigned short* __restrict__ WloK,
             unsigned short* __restrict__ WhiV, unsigned short* __restrict__ WloV,
             unsigned short* __restrict__ Xhi, unsigned short* __restrict__ Xlo,
             unsigned int* __restrict__ obuf)
{
    const int z = blockIdx.z;
    const int tx = threadIdx.x, ty = threadIdx.y;
    if (z == 3) {
        const int t = ty * 32 + tx;
        const int bid = blockIdx.y * 16 + blockIdx.x;   // 0..255
        if (bid == 0 && t < 8)
            obuf[t] = (t < 4) ? 0x3F803F80u : 0u;
        #pragma unroll
        for (int j = 0; j < 4; ++j) {
            const int i = ((bid * 4 + j) * 256 + t) * 8;
            float4 a0 = *(const float4*)&x[i];
            float4 a1 = *(const float4*)&x[i + 4];
            float av[8] = {a0.x, a0.y, a0.z, a0.w, a1.x, a1.y, a1.z, a1.w};
            short8v h, l;
            #pragma unroll
            for (int jj = 0; jj < 8; ++jj) {
                unsigned short hh, ll; split_bf16(av[jj], hh, ll);
                h[jj] = (short)hh; l[jj] = (short)ll;
            }
            *(short8v*)&Xhi[i] = h;
            *(short8v*)&Xlo[i] = l;
        }
        return;
    }
    const int N = (z == 2) ? DV : DKQ;
    if (z == 2 && blockIdx.x >= 2) return;
    const float* __restrict__ W = (z == 0) ? Wq : (z == 1) ? Wk : Wv;
    unsigned short* __restrict__ Whi = (z == 0) ? WhiQ : (z == 1) ? WhiK : WhiV;
    unsigned short* __restrict__ Wlo = (z == 0) ? WloQ : (z == 1) ? WloK : WloV;

    __shared__ float tile[32][33];
    const int n0 = blockIdx.x * 32, k0 = blockIdx.y * 32;
    #pragma unroll
    for (int i = 0; i < 32; i += 8)
        tile[ty + i][tx] = W[(size_t)(k0 + ty + i) * N + n0 + tx];
    __syncthreads();
    #pragma unroll
    for (int i = 0; i < 32; i += 8) {
        unsigned short h, l; split_bf16(tile[tx][ty + i], h, l);
        Whi[(size_t)(n0 + ty + i) * DIN + k0 + tx] = h;
        Wlo[(size_t)(n0 + ty + i) * DIN + k0 + tx] = l;
    }
}

// ---------------------------------------------------------------------------
// QK projection, A-RESIDENT: stage the full 32-row x-strip (hi+lo, 64KB,
// fragment-major: chunk(ks,plane,mt) = 1KB, lane reads chunk+lane*16B) with
// ONE barrier; then a fully-unrolled BARRIER-FREE k-loop. Each of 8 waves
// owns a 64-col strip and streams W fragments straight from global (W planes
// are L2-resident), ping-pong named register sets. 24 MFMA / k-step / wave.
// Grid (2 [Q|K], 128 [32-row strips]), 512 threads.
// ---------------------------------------------------------------------------
__global__ __launch_bounds__(512)
void qk_kernel(const unsigned short* __restrict__ Xhi,
               const unsigned short* __restrict__ Xlo,
               const unsigned short* __restrict__ WhiQ, const unsigned short* __restrict__ WloQ,
               const float* __restrict__ bq,
               const unsigned short* __restrict__ WhiK, const unsigned short* __restrict__ WloK,
               const float* __restrict__ bk,
               unsigned short* __restrict__ Qpk, unsigned short* __restrict__ Kpk)
{
    const int zq = blockIdx.x;                 // 0=Q, 1=K
    const unsigned short* __restrict__ Whi = zq ? WhiK : WhiQ;
    const unsigned short* __restrict__ Wlo = zq ? WloK : WloQ;
    const float* __restrict__ bias = zq ? bk : bq;
    unsigned short* __restrict__ dst = zq ? Kpk : Qpk;

    __shared__ unsigned short LDS[32768];      // 64 KB: 64 chunks x 1KB

    const int t = threadIdx.x;
    const int wave = t >> 6, lane = t & 63;
    const int cl = lane & 15, g2 = lane >> 4;
    const int bm = blockIdx.y * 32;

    // ---- stage A strip: 8 chunks per wave, one barrier ----
    #pragma unroll
    for (int j = 0; j < 8; ++j) {
        const int chunk = wave * 8 + j;
        const int ks = chunk >> 2, plane = (chunk >> 1) & 1, mt = chunk & 1;
        const unsigned short* src = (plane ? Xlo : Xhi)
            + (size_t)(bm + mt * 16 + cl) * DIN + ks * 32 + g2 * 8;
        gll16(src, &LDS[chunk * 512]);
    }
    __syncthreads();

    // ---- barrier-free main loop ----
    const unsigned short* pBh = Whi + (size_t)(wave * 64 + cl) * DIN + g2 * 8;
    const unsigned short* pBl = Wlo + (size_t)(wave * 64 + cl) * DIN + g2 * 8;

    float4v acc[2][4];
    #pragma unroll
    for (int i = 0; i < 2; ++i)
        #pragma unroll
        for (int j = 0; j < 4; ++j)
            acc[i][j] = (float4v){0.f, 0.f, 0.f, 0.f};

    short8v B0h[4], B0l[4], B1h[4], B1l[4];

#define LOADB(KS, BH, BL)                                                     \
    _Pragma("unroll")                                                         \
    for (int nf = 0; nf < 4; ++nf) {                                          \
        BH[nf] = *(const short8v*)(pBh + nf * (16 * DIN) + (KS) * 32);        \
        BL[nf] = *(const short8v*)(pBl + nf * (16 * DIN) + (KS) * 32);        \
    }

#define STEP(KS, BH, BL)                                                      \
    {                                                                         \
        short8v ah[2], al[2];                                                 \
        _Pragma("unroll")                                                     \
        for (int mt = 0; mt < 2; ++mt) {                                      \
            ah[mt] = *(const short8v*)&LDS[((KS) * 4 + mt) * 512 + lane * 8]; \
            al[mt] = *(const short8v*)&LDS[((KS) * 4 + 2 + mt) * 512 + lane * 8]; \
        }                                                                     \
        _Pragma("unroll")                                                     \
        for (int mt = 0; mt < 2; ++mt)                                        \
            _Pragma("unroll")                                                 \
            for (int nf = 0; nf < 4; ++nf) {                                  \
                acc[mt][nf] = __builtin_amdgcn_mfma_f32_16x16x32_bf16(ah[mt], BH[nf], acc[mt][nf], 0, 0, 0); \
                acc[mt][nf] = __builtin_amdgcn_mfma_f32_16x16x32_bf16(al[mt], BH[nf], acc[mt][nf], 0, 0, 0); \
                acc[mt][nf] = __builtin_amdgcn_mfma_f32_16x16x32_bf16(ah[mt], BL[nf], acc[mt][nf], 0, 0, 0); \
            }                                                                 \
    }

    LOADB(0, B0h, B0l);
    #pragma unroll
    for (int kp2 = 0; kp2 < 8; ++kp2) {
        const int ks0 = kp2 * 2;
        LOADB(ks0 + 1, B1h, B1l);
        STEP(ks0, B0h, B0l);
        if (ks0 + 2 < 16) { LOADB(ks0 + 2, B0h, B0l); }
        STEP(ks0 + 1, B1h, B1l);
    }
#undef LOADB
#undef STEP

    // ---- epilogue: bias + relu (+Q scale), hi/lo pack ----
    const float cc = 0.35355339059327373f * 1.4426950408889634f;
    #pragma unroll
    for (int nf = 0; nf < 4; ++nf) {
        const int n = wave * 64 + nf * 16 + cl;
        const float bn = bias[n];
        const int h = n >> 3, d = n & 7;
        #pragma unroll
        for (int mt = 0; mt < 2; ++mt) {
            #pragma unroll
            for (int r = 0; r < 4; ++r) {
                const int row = bm + mt * 16 + g2 * 4 + r;
                const int bb = row >> 10, s = row & 1023;
                float val = fmaxf(acc[mt][nf][r] + bn, 0.0f);
                if (zq == 0) val *= cc;
                const size_t base = ((size_t)((bb << 6) + h) * SEQ + s) * 16 + d;
                unsigned short hi = f32_to_bf16_rne(val);
                dst[base]     = hi;
                dst[base + 8] = f32_to_bf16_rne(val - bf16_bits_to_f32(hi));
            }
        }
    }
}

// ---------------------------------------------------------------------------
// V projection, same A-resident structure: 4 waves, wave tile 32r x 16c,
// 6 MFMA / k-step. Grid (128), 256 threads. Epilogue writes the
// superstep-fragment-major Vsh/Vsl planes the attn gather expects.
// ---------------------------------------------------------------------------
__global__ __launch_bounds__(256)
void v_kernel(const unsigned short* __restrict__ Xhi,
              const unsigned short* __restrict__ Xlo,
              const unsigned short* __restrict__ WhiV, const unsigned short* __restrict__ WloV,
              const float* __restrict__ bv,
              unsigned int* __restrict__ Vsh, unsigned int* __restrict__ Vsl)
{
    __shared__ unsigned short LDS[32768];      // 64 KB

    const int t = threadIdx.x;
    const int wave = t >> 6, lane = t & 63;
    const int cl = lane & 15, g2 = lane >> 4;
    const int bm = blockIdx.x * 32;

    #pragma unroll
    for (int j = 0; j < 16; ++j) {
        const int chunk = wave * 16 + j;
        const int ks = chunk >> 2, plane = (chunk >> 1) & 1, mt = chunk & 1;
        const unsigned short* src = (plane ? Xlo : Xhi)
            + (size_t)(bm + mt * 16 + cl) * DIN + ks * 32 + g2 * 8;
        gll16(src, &LDS[chunk * 512]);
    }
    __syncthreads();

    const unsigned short* pBh = WhiV + (size_t)(wave * 16 + cl) * DIN + g2 * 8;
    const unsigned short* pBl = WloV + (size_t)(wave * 16 + cl) * DIN + g2 * 8;

    float4v acc[2];
    acc[0] = (float4v){0.f, 0.f, 0.f, 0.f};
    acc[1] = (float4v){0.f, 0.f, 0.f, 0.f};

    short8v B0h, B0l, B1h, B1l;

#define VLOADB(KS, BH, BL)                                   \
    BH = *(const short8v*)(pBh + (KS) * 32);                 \
    BL = *(const short8v*)(pBl + (KS) * 32);

#define VSTEP(KS, BH, BL)                                                     \
    {                                                                         \
        short8v ah[2], al[2];                                                 \
        _Pragma("unroll")                                                     \
        for (int mt = 0; mt < 2; ++mt) {                                      \
            ah[mt] = *(const short8v*)&LDS[((KS) * 4 + mt) * 512 + lane * 8]; \
            al[mt] = *(const short8v*)&LDS[((KS) * 4 + 2 + mt) * 512 + lane * 8]; \
        }                                                                     \
        _Pragma("unroll")                                                     \
        for (int mt = 0; mt < 2; ++mt) {                                      \
            acc[mt] = __builtin_amdgcn_mfma_f32_16x16x32_bf16(ah[mt], BH, acc[mt], 0, 0, 0); \
            acc[mt] = __builtin_amdgcn_mfma_f32_16x16x32_bf16(al[mt], BH, acc[mt], 0, 0, 0); \
            acc[mt] = __builtin_amdgcn_mfma_f32_16x16x32_bf16(ah[mt], BL, acc[mt], 0, 0, 0); \
        }                                                                     \
    }

    VLOADB(0, B0h, B0l);
    #pragma unroll
    for (int kp2 = 0; kp2 < 8; ++kp2) {
        const int ks0 = kp2 * 2;
        VLOADB(ks0 + 1, B1h, B1l);
        VSTEP(ks0, B0h, B0l);
        if (ks0 + 2 < 16) { VLOADB(ks0 + 2, B0h, B0l); }
        VSTEP(ks0 + 1, B1h, B1l);
    }
#undef VLOADB
#undef VSTEP

    const int n = wave * 16 + cl;   // head
    const float bn = bv[n];
    #pragma unroll
    for (int mt = 0; mt < 2; ++mt) {
        const int row0 = bm + mt * 16 + g2 * 4;
        const int bb = row0 >> 10, s0 = row0 & 1023;
        // superstep-fragment-major u32 index (matches attn's gather):
        // idx(s) = (s>>5)*16 + ((s>>2)&3)*4 + ((s>>4)&1)*2 + ((s>>1)&1)
        const int idx0 = (s0 >> 5) * 16 + ((s0 >> 2) & 3) * 4 + ((s0 >> 4) & 1) * 2;
        float vv[4]; unsigned short hh[4], ll[4];
        #pragma unroll
        for (int r = 0; r < 4; ++r) {
            vv[r] = fmaxf(acc[mt][r] + bn, 0.0f);
            hh[r] = f32_to_bf16_rne(vv[r]);
            ll[r] = f32_to_bf16_rne(vv[r] - bf16_bits_to_f32(hh[r]));
        }
        const size_t base = (size_t)((bb << 6) + n) * 512 + idx0;
        Vsh[base]     = (unsigned int)hh[0] | ((unsigned int)hh[1] << 16);
        Vsh[base + 1] = (unsigned int)hh[2] | ((unsigned int)hh[3] << 16);
        Vsl[base]     = (unsigned int)ll[0] | ((unsigned int)ll[1] << 16);
        Vsl[base + 1] = (unsigned int)ll[2] | ((unsigned int)ll[3] << 16);
    }
}

// ---------------------------------------------------------------------------
// Attention (UNCHANGED from R10): 8 q-tiles/wave, superstep-2 PV, b128
// V-gather, split-K 4-way, launch_bounds(256,4).
// ---------------------------------------------------------------------------
__global__ __launch_bounds__(256, 4)
void attn_kernel(const unsigned short* __restrict__ Qpk,
                 const unsigned short* __restrict__ Kpk,
                 const unsigned int* __restrict__ Vsh,
                 const unsigned int* __restrict__ Vsl,
                 const unsigned int* __restrict__ obuf,
                 float2* __restrict__ part)
{
    const int bh = blockIdx.x;          // b*64 + h
    const int yb = blockIdx.y;          // 0..7
    const int qhalf = yb >> 2;          // 0..1
    const int kq = yb & 3;              // key quarter
    const int t = threadIdx.x;
    const int wave = t >> 6, lane = t & 63;
    const int g = lane >> 4, cl = lane & 15;

    const unsigned short* __restrict__ qb = Qpk + (size_t)bh * SEQ * 16;
    const unsigned short* __restrict__ kb = Kpk + (size_t)bh * SEQ * 16;

    const int q0 = qhalf * 512 + wave * 128;   // wave covers 128 q-rows

    short8v bq[8];
    #pragma unroll
    for (int qt = 0; qt < 8; ++qt) {
        if (g == 3) { short8v zz = {0,0,0,0,0,0,0,0}; bq[qt] = zz; }
        else bq[qt] = *(const short8v*)(qb + (size_t)(q0 + qt * 16 + cl) * 16 + ((g == 1) ? 8 : 0));
    }

    const int koff = (g >> 1) * 8;
    const unsigned short* kp = kb + kq * 4096 + cl * 16 + koff;

    const unsigned int* ap;
    int astr;
    {
        const size_t vb = (size_t)bh * 512 + kq * 128 + g * 4;
        if (cl == 0)      { ap = Vsh + vb; astr = 16; }
        else if (cl == 2) { ap = Vsl + vb; astr = 16; }
        else if (cl == 1) { ap = obuf;     astr = 0;  }
        else              { ap = obuf + 4; astr = 0;  }
    }

    const float4v c0 = {0.f, 0.f, 0.f, 0.f};
    float4v acc[8];
    #pragma unroll
    for (int qt = 0; qt < 8; ++qt) acc[qt] = c0;

    short8v k0c = *(const short8v*)kp;
    short8v k1c = *(const short8v*)(kp + 256);
    uint4v  auc = *(const uint4v*)ap;

    #pragma unroll
    for (int ss = 0; ss < 8; ++ss) {
        short8v k0n, k1n; uint4v aun;
        if (ss < 7) {
            k0n = *(const short8v*)(kp + 512);
            k1n = *(const short8v*)(kp + 768);
            aun = *(const uint4v*)(ap + astr);
        }
        kp += 512; ap += astr;
        const short8v af = __builtin_bit_cast(short8v, auc);
        #pragma unroll
        for (int qt = 0; qt < 8; ++qt) {
            float4v s0 = __builtin_amdgcn_mfma_f32_16x16x32_bf16(k0c, bq[qt], c0, 0, 0, 0);
            float4v s1 = __builtin_amdgcn_mfma_f32_16x16x32_bf16(k1c, bq[qt], c0, 0, 0, 0);
            float p00 = __builtin_amdgcn_exp2f(s0[0]);
            float p01 = __builtin_amdgcn_exp2f(s0[1]);
            float p02 = __builtin_amdgcn_exp2f(s0[2]);
            float p03 = __builtin_amdgcn_exp2f(s0[3]);
            float p10 = __builtin_amdgcn_exp2f(s1[0]);
            float p11 = __builtin_amdgcn_exp2f(s1[1]);
            float p12 = __builtin_amdgcn_exp2f(s1[2]);
            float p13 = __builtin_amdgcn_exp2f(s1[3]);
            unsigned int pk0 = __builtin_amdgcn_perm(__float_as_uint(p01), __float_as_uint(p00), 0x07060302u);
            unsigned int pk1 = __builtin_amdgcn_perm(__float_as_uint(p03), __float_as_uint(p02), 0x07060302u);
            unsigned int pk2 = __builtin_amdgcn_perm(__float_as_uint(p11), __float_as_uint(p10), 0x07060302u);
            unsigned int pk3 = __builtin_amdgcn_perm(__float_as_uint(p13), __float_as_uint(p12), 0x07060302u);
            uint4v pu = {pk0, pk1, pk2, pk3};
            acc[qt] = __builtin_amdgcn_mfma_f32_16x16x32_bf16(af, __builtin_bit_cast(short8v, pu), acc[qt], 0, 0, 0);
        }
        if (ss < 7) { k0c = k0n; k1c = k1n; auc = aun; }
    }

    if (g == 0) {
        #pragma unroll
        for (int qt = 0; qt < 8; ++qt) {
            const int row = q0 + qt * 16 + cl;
            float2 pr;
            pr.x = acc[qt][0] + acc[qt][2];
            pr.y = acc[qt][1];
            part[(size_t)(kq * 256 + bh) * SEQ + row] = pr;
        }
    }
}

// ---------------------------------------------------------------------------
// Merge split-K quarters + positional embedding. (unchanged)
// ---------------------------------------------------------------------------
__global__ __launch_bounds__(256)
void merge_kernel(const float2* __restrict__ part, float* __restrict__ out)
{
    const int tid = blockIdx.x * 256 + threadIdx.x;  // = (b*1024+q)*64+h
    const int h = tid & 63;
    const int q = (tid >> 6) & 1023;
    const int b = tid >> 16;
    const int bh = (b << 6) + h;
    float num = 0.f, den = 0.f;
    #pragma unroll
    for (int kq = 0; kq < 4; ++kq) {
        float2 p = part[(size_t)(kq * 256 + bh) * SEQ + q];
        num += p.x; den += p.y;
    }
    const float fr = __builtin_amdgcn_exp2f((float)(h & 31) * -0.4152410118609203f);
    const float pe = (h < 32) ? cosf((float)q * fr) : sinf((float)q * fr);
    out[tid] = num / den + pe;
}

// ---------------------------------------------------------------------------
extern "C" void kernel_launch(void* const* d_in, const int* in_sizes, int n_in,
                              void* d_out, int out_size, void* d_ws, size_t ws_size,
                              hipStream_t stream)
{
    const float* x  = (const float*)d_in[0];
    const float* Wq = (const float*)d_in[1];
    const float* bq = (const float*)d_in[2];
    const float* Wk = (const float*)d_in[3];
    const float* bk = (const float*)d_in[4];
    const float* Wv = (const float*)d_in[5];
    const float* bv = (const float*)d_in[6];
    float* out = (float*)d_out;

    // ws layout:
    //   Qpk 8.39MB | Kpk 8.39MB | Vsh .52 | Vsl .52 | obuf 256B |
    //   Xhi 4.19MB | Xlo 4.19MB  (part[8MB] aliases Xhi: X dead after proj) |
    //   W planes 2.23MB
    unsigned short* Qpk = (unsigned short*)d_ws;
    unsigned short* Kpk = Qpk + (size_t)BATCH * NH * SEQ * 16;
    unsigned int* Vsh = (unsigned int*)(Kpk + (size_t)BATCH * NH * SEQ * 16);
    unsigned int* Vsl = Vsh + (size_t)BATCH * NH * (SEQ / 2);
    unsigned int* obuf = Vsl + (size_t)BATCH * NH * (SEQ / 2);
    unsigned short* Xhi = (unsigned short*)(obuf + 64);
    unsigned short* Xlo = Xhi + (size_t)BATCH * SEQ * DIN;
    float2* part = (float2*)Xhi;   // aliases X planes
    unsigned short* WhiQ = Xlo + (size_t)BATCH * SEQ * DIN;
    unsigned short* WloQ = WhiQ + (size_t)DIN * DKQ;
    unsigned short* WhiK = WloQ + (size_t)DIN * DKQ;
    unsigned short* WloK = WhiK + (size_t)DIN * DKQ;
    unsigned short* WhiV = WloK + (size_t)DIN * DKQ;
    unsigned short* WloV = WhiV + (size_t)DIN * DV;

    prepack<<<dim3(16, 16, 4), dim3(32, 8), 0, stream>>>(
        x, Wq, Wk, Wv, WhiQ, WloQ, WhiK, WloK, WhiV, WloV, Xhi, Xlo, obuf);
    qk_kernel<<<dim3(2, 128), 512, 0, stream>>>(
        Xhi, Xlo, WhiQ, WloQ, bq, WhiK, WloK, bk, Qpk, Kpk);
    v_kernel<<<dim3(128), 256, 0, stream>>>(
        Xhi, Xlo, WhiV, WloV, bv, Vsh, Vsl);
    attn_kernel<<<dim3(256, 8), 256, 0, stream>>>(Qpk, Kpk, Vsh, Vsl, obuf, part);
    merge_kernel<<<dim3((BATCH * SEQ * DV) / 256), 256, 0, stream>>>(part, out);
}

// Round 12
// 81.992 us; speedup vs baseline: 1.2380x; 1.2380x over previous
//
#include <hip/hip_runtime.h>
#include <math.h>

#define BATCH 4
#define SEQ   1024
#define DIN   512
#define DKQ   512
#define DV    64
#define NH    64

typedef __attribute__((ext_vector_type(8))) short short8v;   // 8 bf16 = 4 VGPRs
typedef __attribute__((ext_vector_type(4))) float float4v;
typedef __attribute__((ext_vector_type(4))) unsigned int uint4v;

__device__ __forceinline__ void split_bf16(float f, unsigned short& hi, unsigned short& lo) {
    unsigned int u = __float_as_uint(f);
    hi = (unsigned short)(u >> 16);
    float l = f - __uint_as_float(u & 0xFFFF0000u);
    lo = (unsigned short)(__float_as_uint(l) >> 16);
}
__device__ __forceinline__ unsigned short f32_to_bf16_rne(float f) {
    unsigned int u = __float_as_uint(f);
    u += 0x7FFFu + ((u >> 16) & 1u);
    return (unsigned short)(u >> 16);
}
__device__ __forceinline__ float bf16_bits_to_f32(unsigned short s) {
    return __uint_as_float((unsigned int)s << 16);
}

// async global -> LDS, 16B per lane; LDS dest = wave-uniform base + lane*16
__device__ __forceinline__ void gll16(const unsigned short* g, unsigned short* l) {
    __builtin_amdgcn_global_load_lds(
        (const __attribute__((address_space(1))) unsigned int*)(g),
        (__attribute__((address_space(3))) unsigned int*)(l),
        16, 0, 0);
}

// ---------------------------------------------------------------------------
// prepack: z=0..2 -> W transpose+split planes; z=3 -> x split planes + obuf.
// grid (16,16,4), block (32,8).
// ---------------------------------------------------------------------------
__global__ __launch_bounds__(256)
void prepack(const float* __restrict__ x,
             const float* __restrict__ Wq, const float* __restrict__ Wk,
             const float* __restrict__ Wv,
             unsigned short* __restrict__ WhiQ, unsigned short* __restrict__ WloQ,
             unsigned short* __restrict__ WhiK, unsigned short* __restrict__ WloK,
             unsigned short* __restrict__ WhiV, unsigned short* __restrict__ WloV,
             unsigned short* __restrict__ Xhi, unsigned short* __restrict__ Xlo,
             unsigned int* __restrict__ obuf)
{
    const int z = blockIdx.z;
    const int tx = threadIdx.x, ty = threadIdx.y;
    if (z == 3) {
        const int t = ty * 32 + tx;
        const int bid = blockIdx.y * 16 + blockIdx.x;   // 0..255
        if (bid == 0 && t < 8)
            obuf[t] = (t < 4) ? 0x3F803F80u : 0u;
        #pragma unroll
        for (int j = 0; j < 4; ++j) {
            const int i = ((bid * 4 + j) * 256 + t) * 8;
            float4 a0 = *(const float4*)&x[i];
            float4 a1 = *(const float4*)&x[i + 4];
            float av[8] = {a0.x, a0.y, a0.z, a0.w, a1.x, a1.y, a1.z, a1.w};
            short8v h, l;
            #pragma unroll
            for (int jj = 0; jj < 8; ++jj) {
                unsigned short hh, ll; split_bf16(av[jj], hh, ll);
                h[jj] = (short)hh; l[jj] = (short)ll;
            }
            *(short8v*)&Xhi[i] = h;
            *(short8v*)&Xlo[i] = l;
        }
        return;
    }
    const int N = (z == 2) ? DV : DKQ;
    if (z == 2 && blockIdx.x >= 2) return;
    const float* __restrict__ W = (z == 0) ? Wq : (z == 1) ? Wk : Wv;
    unsigned short* __restrict__ Whi = (z == 0) ? WhiQ : (z == 1) ? WhiK : WhiV;
    unsigned short* __restrict__ Wlo = (z == 0) ? WloQ : (z == 1) ? WloK : WloV;

    __shared__ float tile[32][33];
    const int n0 = blockIdx.x * 32, k0 = blockIdx.y * 32;
    #pragma unroll
    for (int i = 0; i < 32; i += 8)
        tile[ty + i][tx] = W[(size_t)(k0 + ty + i) * N + n0 + tx];
    __syncthreads();
    #pragma unroll
    for (int i = 0; i < 32; i += 8) {
        unsigned short h, l; split_bf16(tile[tx][ty + i], h, l);
        Whi[(size_t)(n0 + ty + i) * DIN + k0 + tx] = h;
        Wlo[(size_t)(n0 + ty + i) * DIN + k0 + tx] = l;
    }
}

// ---------------------------------------------------------------------------
// Projection v6: R9's proven main loop (global_load_lds 16B into fragment-
// major LDS chunks, 2 buffers x 32KB, depth-1 prefetch, __syncthreads/step)
// + NEW coalesced epilogue: per-fragment LDS-bounce transpose so Qpk/Kpk
// stores are one dwordx4 per lane (two 512B contiguous runs) instead of 64
// scattered 2B stores per thread.
// Block 128x128 (z=2: 128x64), 8 waves (2Mx4N), BK=32, 16 K-steps.
// ---------------------------------------------------------------------------
__global__ __launch_bounds__(512)
void proj_kernel(const unsigned short* __restrict__ Xhi,
                 const unsigned short* __restrict__ Xlo,
                 const unsigned short* __restrict__ WhiQ, const unsigned short* __restrict__ WloQ,
                 const float* __restrict__ bq,
                 const unsigned short* __restrict__ WhiK, const unsigned short* __restrict__ WloK,
                 const float* __restrict__ bk,
                 const unsigned short* __restrict__ WhiV, const unsigned short* __restrict__ WloV,
                 const float* __restrict__ bv,
                 unsigned short* __restrict__ Qpk, unsigned short* __restrict__ Kpk,
                 unsigned int* __restrict__ Vsh, unsigned int* __restrict__ Vsl)
{
    const int z = blockIdx.z;
    if (z == 2 && blockIdx.x != 0) return;
    const unsigned short* __restrict__ Whi = (z == 0) ? WhiQ : (z == 1) ? WhiK : WhiV;
    const unsigned short* __restrict__ Wlo = (z == 0) ? WloQ : (z == 1) ? WloK : WloV;
    const float* __restrict__ bias = (z == 0) ? bq : (z == 1) ? bk : bv;

    __shared__ unsigned short LDS[2][16384];   // 64 KB

    const int t = threadIdx.x;
    const int wave = t >> 6, lane = t & 63;
    const int cl = lane & 15, g2 = lane >> 4;
    const int bm  = blockIdx.y * 128;
    const int cbb = (z == 2) ? 0 : blockIdx.x * 128;
    const int wr = wave >> 2, wc = wave & 3;   // 2x4 wave grid
    const int NF = (z == 2) ? 1 : 2;

    // staging sources (per lane); advance +32 ushorts per K-step
    const unsigned short* sAh = Xhi + (size_t)(bm + wave * 16 + cl) * DIN + g2 * 8;
    const unsigned short* sAl = Xlo + (size_t)(bm + wave * 16 + cl) * DIN + g2 * 8;
    const bool bvalid = (z != 2) || (wave < 4);
    const size_t bro = (size_t)(cbb + wave * 16 + cl) * DIN + g2 * 8;
    const unsigned short* sBh = Whi + (bvalid ? bro : 0);
    const unsigned short* sBl = Wlo + (bvalid ? bro : 0);

    auto stage = [&](int step, int bufIdx) {
        unsigned short* L = &LDS[bufIdx][0];
        const int kofs = step * 32;
        gll16(sAh + kofs, L + (wave) * 512);
        gll16(sAl + kofs, L + (wave + 8) * 512);
        if (bvalid) {
            gll16(sBh + kofs, L + (wave + 16) * 512);
            gll16(sBl + kofs, L + (wave + 24) * 512);
        }
    };

    float4v acc[4][2];
    #pragma unroll
    for (int i = 0; i < 4; ++i)
        #pragma unroll
        for (int j = 0; j < 2; ++j)
            acc[i][j] = (float4v){0.f, 0.f, 0.f, 0.f};

    stage(0, 0);
    __syncthreads();

    #pragma unroll
    for (int ks = 0; ks < 16; ++ks) {
        const int cur = ks & 1;
        if (ks < 15) stage(ks + 1, cur ^ 1);

        const unsigned short* L = &LDS[cur][0];
        short8v af_h[4], af_l[4], bf_h[2], bf_l[2];
        #pragma unroll
        for (int mt = 0; mt < 4; ++mt) {
            af_h[mt] = *(const short8v*)(L + (wr * 4 + mt) * 512 + lane * 8);
            af_l[mt] = *(const short8v*)(L + (8 + wr * 4 + mt) * 512 + lane * 8);
        }
        #pragma unroll
        for (int nf = 0; nf < 2; ++nf) {
            if (nf < NF) {
                bf_h[nf] = *(const short8v*)(L + (16 + wc * NF + nf) * 512 + lane * 8);
                bf_l[nf] = *(const short8v*)(L + (24 + wc * NF + nf) * 512 + lane * 8);
            }
        }
        #pragma unroll
        for (int mt = 0; mt < 4; ++mt)
            #pragma unroll
            for (int nf = 0; nf < 2; ++nf) {
                if (nf >= NF) continue;
                acc[mt][nf] = __builtin_amdgcn_mfma_f32_16x16x32_bf16(af_h[mt], bf_h[nf], acc[mt][nf], 0, 0, 0);
                acc[mt][nf] = __builtin_amdgcn_mfma_f32_16x16x32_bf16(af_l[mt], bf_h[nf], acc[mt][nf], 0, 0, 0);
                acc[mt][nf] = __builtin_amdgcn_mfma_f32_16x16x32_bf16(af_h[mt], bf_l[nf], acc[mt][nf], 0, 0, 0);
            }
        __syncthreads();   // drains prefetch + LDS reads before buffer swap
    }

    const float cc = 0.35355339059327373f * 1.4426950408889634f;
    if (z == 2) {
        const int n = wc * 16 + cl;   // head
        const float bn = bias[n];
        #pragma unroll
        for (int mt = 0; mt < 4; ++mt) {
            const int row0 = bm + wr * 64 + mt * 16 + g2 * 4;
            const int bb = row0 >> 10, s0 = row0 & 1023;
            // superstep-fragment-major u32 index (matches attn's gather):
            // idx(s) = (s>>5)*16 + ((s>>2)&3)*4 + ((s>>4)&1)*2 + ((s>>1)&1)
            const int idx0 = (s0 >> 5) * 16 + ((s0 >> 2) & 3) * 4 + ((s0 >> 4) & 1) * 2;
            float vv[4]; unsigned short hh[4], ll[4];
            #pragma unroll
            for (int r = 0; r < 4; ++r) {
                vv[r] = fmaxf(acc[mt][0][r] + bn, 0.0f);
                hh[r] = f32_to_bf16_rne(vv[r]);
                ll[r] = f32_to_bf16_rne(vv[r] - bf16_bits_to_f32(hh[r]));
            }
            const size_t base = (size_t)((bb << 6) + n) * 512 + idx0;
            Vsh[base]     = (unsigned int)hh[0] | ((unsigned int)hh[1] << 16);
            Vsh[base + 1] = (unsigned int)hh[2] | ((unsigned int)hh[3] << 16);
            Vsl[base]     = (unsigned int)ll[0] | ((unsigned int)ll[1] << 16);
            Vsl[base + 1] = (unsigned int)ll[2] | ((unsigned int)ll[3] << 16);
        }
    } else {
        // ---- coalesced epilogue via per-wave LDS bounce (1KB region) ----
        unsigned short* __restrict__ dst = (z == 0) ? Qpk : Kpk;
        unsigned short* Lb = &LDS[0][0] + wave * 512;   // 1KB per wave, private
        const int hd = cl >> 3, d = cl & 7;             // write-side coords
        const int lhd = lane >> 5, lrem = lane & 31;    // read-side coords
        const int ls = lrem >> 1, lhalf = lrem & 1;
        #pragma unroll
        for (int mt = 0; mt < 4; ++mt) {
            const int row0 = bm + wr * 64 + mt * 16;    // 16-aligned
            const int bb = row0 >> 10, s0 = row0 & 1023;
            #pragma unroll
            for (int nf = 0; nf < 2; ++nf) {
                const int nbase = cbb + wc * 32 + nf * 16;
                const float bn = bias[nbase + cl];
                #pragma unroll
                for (int r = 0; r < 4; ++r) {
                    float val = fmaxf(acc[mt][nf][r] + bn, 0.0f);
                    if (z == 0) val *= cc;
                    unsigned short hi = f32_to_bf16_rne(val);
                    unsigned short lo = f32_to_bf16_rne(val - bf16_bits_to_f32(hi));
                    const int sl = g2 * 4 + r;
                    Lb[hd * 256 + sl * 16 + d]     = hi;
                    Lb[hd * 256 + sl * 16 + 8 + d] = lo;
                }
                // read back in store order: lane -> (head, s, half), 16B each
                short8v vv = *(const short8v*)(Lb + lhd * 256 + ls * 16 + lhalf * 8);
                const int h = (nbase >> 3) + lhd;
                const size_t off = ((size_t)((bb << 6) + h) * SEQ + s0 + ls) * 16 + lhalf * 8;
                *(short8v*)(dst + off) = vv;
            }
        }
    }
}

// ---------------------------------------------------------------------------
// Attention (UNCHANGED from R10): 8 q-tiles/wave, superstep-2 PV, b128
// V-gather, split-K 4-way, launch_bounds(256,4).
// ---------------------------------------------------------------------------
__global__ __launch_bounds__(256, 4)
void attn_kernel(const unsigned short* __restrict__ Qpk,
                 const unsigned short* __restrict__ Kpk,
                 const unsigned int* __restrict__ Vsh,
                 const unsigned int* __restrict__ Vsl,
                 const unsigned int* __restrict__ obuf,
                 float2* __restrict__ part)
{
    const int bh = blockIdx.x;          // b*64 + h
    const int yb = blockIdx.y;          // 0..7
    const int qhalf = yb >> 2;          // 0..1
    const int kq = yb & 3;              // key quarter
    const int t = threadIdx.x;
    const int wave = t >> 6, lane = t & 63;
    const int g = lane >> 4, cl = lane & 15;

    const unsigned short* __restrict__ qb = Qpk + (size_t)bh * SEQ * 16;
    const unsigned short* __restrict__ kb = Kpk + (size_t)bh * SEQ * 16;

    const int q0 = qhalf * 512 + wave * 128;   // wave covers 128 q-rows

    short8v bq[8];
    #pragma unroll
    for (int qt = 0; qt < 8; ++qt) {
        if (g == 3) { short8v zz = {0,0,0,0,0,0,0,0}; bq[qt] = zz; }
        else bq[qt] = *(const short8v*)(qb + (size_t)(q0 + qt * 16 + cl) * 16 + ((g == 1) ? 8 : 0));
    }

    const int koff = (g >> 1) * 8;
    const unsigned short* kp = kb + kq * 4096 + cl * 16 + koff;

    const unsigned int* ap;
    int astr;
    {
        const size_t vb = (size_t)bh * 512 + kq * 128 + g * 4;
        if (cl == 0)      { ap = Vsh + vb; astr = 16; }
        else if (cl == 2) { ap = Vsl + vb; astr = 16; }
        else if (cl == 1) { ap = obuf;     astr = 0;  }
        else              { ap = obuf + 4; astr = 0;  }
    }

    const float4v c0 = {0.f, 0.f, 0.f, 0.f};
    float4v acc[8];
    #pragma unroll
    for (int qt = 0; qt < 8; ++qt) acc[qt] = c0;

    short8v k0c = *(const short8v*)kp;
    short8v k1c = *(const short8v*)(kp + 256);
    uint4v  auc = *(const uint4v*)ap;

    #pragma unroll
    for (int ss = 0; ss < 8; ++ss) {
        short8v k0n, k1n; uint4v aun;
        if (ss < 7) {
            k0n = *(const short8v*)(kp + 512);
            k1n = *(const short8v*)(kp + 768);
            aun = *(const uint4v*)(ap + astr);
        }
        kp += 512; ap += astr;
        const short8v af = __builtin_bit_cast(short8v, auc);
        #pragma unroll
        for (int qt = 0; qt < 8; ++qt) {
            float4v s0 = __builtin_amdgcn_mfma_f32_16x16x32_bf16(k0c, bq[qt], c0, 0, 0, 0);
            float4v s1 = __builtin_amdgcn_mfma_f32_16x16x32_bf16(k1c, bq[qt], c0, 0, 0, 0);
            float p00 = __builtin_amdgcn_exp2f(s0[0]);
            float p01 = __builtin_amdgcn_exp2f(s0[1]);
            float p02 = __builtin_amdgcn_exp2f(s0[2]);
            float p03 = __builtin_amdgcn_exp2f(s0[3]);
            float p10 = __builtin_amdgcn_exp2f(s1[0]);
            float p11 = __builtin_amdgcn_exp2f(s1[1]);
            float p12 = __builtin_amdgcn_exp2f(s1[2]);
            float p13 = __builtin_amdgcn_exp2f(s1[3]);
            unsigned int pk0 = __builtin_amdgcn_perm(__float_as_uint(p01), __float_as_uint(p00), 0x07060302u);
            unsigned int pk1 = __builtin_amdgcn_perm(__float_as_uint(p03), __float_as_uint(p02), 0x07060302u);
            unsigned int pk2 = __builtin_amdgcn_perm(__float_as_uint(p11), __float_as_uint(p10), 0x07060302u);
            unsigned int pk3 = __builtin_amdgcn_perm(__float_as_uint(p13), __float_as_uint(p12), 0x07060302u);
            uint4v pu = {pk0, pk1, pk2, pk3};
            acc[qt] = __builtin_amdgcn_mfma_f32_16x16x32_bf16(af, __builtin_bit_cast(short8v, pu), acc[qt], 0, 0, 0);
        }
        if (ss < 7) { k0c = k0n; k1c = k1n; auc = aun; }
    }

    if (g == 0) {
        #pragma unroll
        for (int qt = 0; qt < 8; ++qt) {
            const int row = q0 + qt * 16 + cl;
            float2 pr;
            pr.x = acc[qt][0] + acc[qt][2];
            pr.y = acc[qt][1];
            part[(size_t)(kq * 256 + bh) * SEQ + row] = pr;
        }
    }
}

// ---------------------------------------------------------------------------
// Merge split-K quarters + positional embedding. (unchanged)
// ---------------------------------------------------------------------------
__global__ __launch_bounds__(256)
void merge_kernel(const float2* __restrict__ part, float* __restrict__ out)
{
    const int tid = blockIdx.x * 256 + threadIdx.x;  // = (b*1024+q)*64+h
    const int h = tid & 63;
    const int q = (tid >> 6) & 1023;
    const int b = tid >> 16;
    const int bh = (b << 6) + h;
    float num = 0.f, den = 0.f;
    #pragma unroll
    for (int kq = 0; kq < 4; ++kq) {
        float2 p = part[(size_t)(kq * 256 + bh) * SEQ + q];
        num += p.x; den += p.y;
    }
    const float fr = __builtin_amdgcn_exp2f((float)(h & 31) * -0.4152410118609203f);
    const float pe = (h < 32) ? cosf((float)q * fr) : sinf((float)q * fr);
    out[tid] = num / den + pe;
}

// ---------------------------------------------------------------------------
extern "C" void kernel_launch(void* const* d_in, const int* in_sizes, int n_in,
                              void* d_out, int out_size, void* d_ws, size_t ws_size,
                              hipStream_t stream)
{
    const float* x  = (const float*)d_in[0];
    const float* Wq = (const float*)d_in[1];
    const float* bq = (const float*)d_in[2];
    const float* Wk = (const float*)d_in[3];
    const float* bk = (const float*)d_in[4];
    const float* Wv = (const float*)d_in[5];
    const float* bv = (const float*)d_in[6];
    float* out = (float*)d_out;

    // ws layout:
    //   Qpk 8.39MB | Kpk 8.39MB | Vsh .52 | Vsl .52 | obuf 256B |
    //   Xhi 4.19MB | Xlo 4.19MB  (part[8MB] aliases Xhi: X dead after proj) |
    //   W planes 2.23MB
    unsigned short* Qpk = (unsigned short*)d_ws;
    unsigned short* Kpk = Qpk + (size_t)BATCH * NH * SEQ * 16;
    unsigned int* Vsh = (unsigned int*)(Kpk + (size_t)BATCH * NH * SEQ * 16);
    unsigned int* Vsl = Vsh + (size_t)BATCH * NH * (SEQ / 2);
    unsigned int* obuf = Vsl + (size_t)BATCH * NH * (SEQ / 2);
    unsigned short* Xhi = (unsigned short*)(obuf + 64);
    unsigned short* Xlo = Xhi + (size_t)BATCH * SEQ * DIN;
    float2* part = (float2*)Xhi;   // aliases X planes
    unsigned short* WhiQ = Xlo + (size_t)BATCH * SEQ * DIN;
    unsigned short* WloQ = WhiQ + (size_t)DIN * DKQ;
    unsigned short* WhiK = WloQ + (size_t)DIN * DKQ;
    unsigned short* WloK = WhiK + (size_t)DIN * DKQ;
    unsigned short* WhiV = WloK + (size_t)DIN * DKQ;
    unsigned short* WloV = WhiV + (size_t)DIN * DV;

    prepack<<<dim3(16, 16, 4), dim3(32, 8), 0, stream>>>(
        x, Wq, Wk, Wv, WhiQ, WloQ, WhiK, WloK, WhiV, WloV, Xhi, Xlo, obuf);
    proj_kernel<<<dim3(4, 32, 3), 512, 0, stream>>>(
        Xhi, Xlo, WhiQ, WloQ, bq, WhiK, WloK, bk, WhiV, WloV, bv, Qpk, Kpk, Vsh, Vsl);
    attn_kernel<<<dim3(256, 8), 256, 0, stream>>>(Qpk, Kpk, Vsh, Vsl, obuf, part);
    merge_kernel<<<dim3((BATCH * SEQ * DV) / 256), 256, 0, stream>>>(part, out);
}